// Round 5
// baseline (209.632 us; speedup 1.0000x reference)
//
#include <hip/hip_runtime.h>

// Batched 3D affine spatial transformer: vol [B=4,160,192,160,1] fp32, trf [4,4,4] fp32.
// R5: R4 showed the scattered-gather VMEM path is the bind (miss-buffer x latency;
// more MLP didn't help). Stage each block's source bbox into LDS with dense coalesced
// row loads, then gather the 8 corners from LDS (no miss buffers, stride-1 lanes).
// Block-uniform capacity check + full global-gather fallback keeps it correct for any trf.
constexpr int D = 160, H = 192, W = 160, B = 4;
constexpr int V  = D * H * W;
constexpr int HW = H * W;
constexpr int CAP = 13312;   // floats of LDS = 52 KB -> 3 blocks/CU (160 KB LDS/CU)

struct DimS { int i0; float w0; };

// Equivalent to neuron.utils interpn clipping (verified R3):
//   c = clip(loc,0,max); i0 = min((int)c, max-1); i1 = i0+1; w0 = (i0+1)-c.
__device__ __forceinline__ DimS prep(float loc, float maxv, int maxi) {
    float c  = fminf(fmaxf(loc, 0.0f), maxv);
    int  i0  = min((int)c, maxi - 1);
    DimS s; s.i0 = i0; s.w0 = (float)(i0 + 1) - c;
    return s;
}

// Range of i0 for loc in [lo,hi]: monotone clamp+floor+min -> evaluate at ends.
__device__ __forceinline__ int i0_range(float lo, float hi, float maxv, int maxi, int* n) {
    int iLo = min((int)fminf(fmaxf(lo, 0.0f), maxv), maxi - 1);
    int iHi = min((int)fminf(fmaxf(hi, 0.0f), maxv), maxi - 1);
    *n = iHi - iLo + 2;          // planes [iLo, iHi+1]
    return iLo;
}

__device__ __forceinline__ float trilerp_g(const float* __restrict__ vb,
                                           DimS sd, DimS sh, DimS sw) {
    const float* p0 = vb + ((sd.i0 * H + sh.i0) * W + sw.i0);
    float2 v00, v01, v10, v11;
    __builtin_memcpy(&v00, p0,          8);
    __builtin_memcpy(&v01, p0 + W,      8);
    __builtin_memcpy(&v10, p0 + HW,     8);
    __builtin_memcpy(&v11, p0 + HW + W, 8);
    const float pd00 = fmaf(sw.w0, v00.x - v00.y, v00.y);
    const float pd01 = fmaf(sw.w0, v01.x - v01.y, v01.y);
    const float pd10 = fmaf(sw.w0, v10.x - v10.y, v10.y);
    const float pd11 = fmaf(sw.w0, v11.x - v11.y, v11.y);
    const float q0 = fmaf(sh.w0, pd00 - pd01, pd01);
    const float q1 = fmaf(sh.w0, pd10 - pd11, pd11);
    return fmaf(sd.w0, q0 - q1, q1);
}

__global__ __launch_bounds__(256) void st_affine_kernel(
        const float* __restrict__ vol, const float* __restrict__ trf,
        float* __restrict__ out) {
    __shared__ float smem[CAP];

    const int b  = blockIdx.z;
    const int d0 = blockIdx.y * 4;            // 4 voxels/thread along d
    const int hblk = blockIdx.x / 5;          // grid.x = 5 w-tiles * 24 h-tiles
    const int wblk = blockIdx.x - hblk * 5;
    const int w = wblk * 32 + threadIdx.x;
    const int h = hblk * 8  + threadIdx.y;

    const float* __restrict__ A = trf + b * 16;   // wave-uniform -> scalar loads
    const float a00 = A[0], a01 = A[1], a02 = A[2],  a03 = A[3];
    const float a10 = A[4], a11 = A[5], a12 = A[6],  a13 = A[7];
    const float a20 = A[8], a21 = A[9], a22 = A[10], a23 = A[11];

    constexpr float cd = (D - 1) * 0.5f;
    constexpr float ch = (H - 1) * 0.5f;
    constexpr float cw = (W - 1) * 0.5f;

    // ---- block bbox via interval arithmetic (affine -> extrema at tile corners) ----
    const float mdc = (float)d0 + 1.5f - cd;              // tile center (d)
    const float mhc = (float)(hblk * 8)  + 3.5f  - ch;
    const float mwc = (float)(wblk * 32) + 15.5f - cw;
    const float lcD = cd + fmaf(a00, mdc, fmaf(a01, mhc, fmaf(a02, mwc, a03)));
    const float lcH = ch + fmaf(a10, mdc, fmaf(a11, mhc, fmaf(a12, mwc, a13)));
    const float lcW = cw + fmaf(a20, mdc, fmaf(a21, mhc, fmaf(a22, mwc, a23)));
    // +0.02 margin covers fp rounding differences vs the per-voxel fmaf chain
    const float rD = fabsf(a00) * 1.5f + fabsf(a01) * 3.5f + fabsf(a02) * 15.5f + 0.02f;
    const float rH = fabsf(a10) * 1.5f + fabsf(a11) * 3.5f + fabsf(a12) * 15.5f + 0.02f;
    const float rW = fabsf(a20) * 1.5f + fabsf(a21) * 3.5f + fabsf(a22) * 15.5f + 0.02f;

    int zn, yn, xn;
    const int zlo = i0_range(lcD - rD, lcD + rD, (float)(D - 1), D - 1, &zn);
    const int ylo = i0_range(lcH - rH, lcH + rH, (float)(H - 1), H - 1, &yn);
    const int xlo = i0_range(lcW - rW, lcW + rW, (float)(W - 1), W - 1, &xn);
    const bool fits = (xn <= 64) && (zn * yn * xn <= CAP);   // block-uniform

    const float* __restrict__ vb = vol + (size_t)b * V;

    // per-thread sample location for k=0; then loc += column 0 of A per d-step
    const float md = (float)d0 - cd;
    const float mh = (float)h  - ch;
    const float mw = (float)w  - cw;
    float ld = cd + fmaf(a00, md, fmaf(a01, mh, fmaf(a02, mw, a03)));
    float lh = ch + fmaf(a10, md, fmaf(a11, mh, fmaf(a12, mw, a13)));
    float lw = cw + fmaf(a20, md, fmaf(a21, mh, fmaf(a22, mw, a23)));

    float res[4];

    if (fits) {
        // ---- stage bbox rows into LDS (dense, coalesced, batched for MLP) ----
        const int t      = threadIdx.y * 32 + threadIdx.x;
        const int lane   = t & 63;
        const int waveId = t >> 6;                 // 4 waves
        const int R = zn * yn;                     // rows; flat row r = zi*yn + yi
        int zi = 0, yi = waveId;
        if (yi >= yn) { yi -= yn; ++zi; }          // waveId<=3, yn>=2 -> one wrap max
        int r = waveId;
        while (r < R) {
            float vbuf[8];
            int zi2 = zi, yi2 = yi;
            #pragma unroll
            for (int k = 0; k < 8; ++k) {          // 8 independent loads in flight
                const int rk = r + 4 * k;
                float val = 0.0f;
                if (rk < R && lane < xn)
                    val = vb[(size_t)((zlo + zi2) * H + (ylo + yi2)) * W + xlo + lane];
                vbuf[k] = val;
                yi2 += 4;                          // step 4 rows; yn>=2 -> <=2 wraps
                if (yi2 >= yn) { yi2 -= yn; ++zi2; }
                if (yi2 >= yn) { yi2 -= yn; ++zi2; }
            }
            #pragma unroll
            for (int k = 0; k < 8; ++k) {
                const int rk = r + 4 * k;
                if (rk < R && lane < xn) smem[rk * xn + lane] = vbuf[k];
            }
            zi = zi2; yi = yi2;
            r += 32;
        }
        __syncthreads();

        // ---- gather 8 corners from LDS ----
        const int pl = yn * xn;
        #pragma unroll
        for (int k = 0; k < 4; ++k) {
            const DimS sd = prep(ld, (float)(D - 1), D - 1);
            const DimS sh = prep(lh, (float)(H - 1), H - 1);
            const DimS sw = prep(lw, (float)(W - 1), W - 1);
            const int base = ((sd.i0 - zlo) * yn + (sh.i0 - ylo)) * xn + (sw.i0 - xlo);
            const float v00x = smem[base],           v00y = smem[base + 1];
            const float v01x = smem[base + xn],      v01y = smem[base + xn + 1];
            const float v10x = smem[base + pl],      v10y = smem[base + pl + 1];
            const float v11x = smem[base + pl + xn], v11y = smem[base + pl + xn + 1];
            const float pd00 = fmaf(sw.w0, v00x - v00y, v00y);
            const float pd01 = fmaf(sw.w0, v01x - v01y, v01y);
            const float pd10 = fmaf(sw.w0, v10x - v10y, v10y);
            const float pd11 = fmaf(sw.w0, v11x - v11y, v11y);
            const float q0 = fmaf(sh.w0, pd00 - pd01, pd01);
            const float q1 = fmaf(sh.w0, pd10 - pd11, pd11);
            res[k] = fmaf(sd.w0, q0 - q1, q1);
            ld += a00; lh += a10; lw += a20;
        }
    } else {
        // ---- fallback: direct global gather (R4 path), correct for any trf ----
        #pragma unroll
        for (int k = 0; k < 4; ++k) {
            const DimS sd = prep(ld, (float)(D - 1), D - 1);
            const DimS sh = prep(lh, (float)(H - 1), H - 1);
            const DimS sw = prep(lw, (float)(W - 1), W - 1);
            res[k] = trilerp_g(vb, sd, sh, sw);
            ld += a00; lh += a10; lw += a20;
        }
    }

    float* ob = out + (size_t)b * V + (size_t)h * W + w;
    #pragma unroll
    for (int k = 0; k < 4; ++k)
        __builtin_nontemporal_store(res[k], ob + (size_t)(d0 + k) * HW);
}

extern "C" void kernel_launch(void* const* d_in, const int* in_sizes, int n_in,
                              void* d_out, int out_size, void* d_ws, size_t ws_size,
                              hipStream_t stream) {
    const float* vol = (const float*)d_in[0];
    const float* trf = (const float*)d_in[1];
    float* out = (float*)d_out;

    dim3 grid((H / 8) * (W / 32), D / 4, B);   // (120, 40, 4) = 19,200 blocks
    dim3 block(32, 8, 1);
    st_affine_kernel<<<grid, block, 0, stream>>>(vol, trf, out);
}